// Round 1
// baseline (820.546 us; speedup 1.0000x reference)
//
#include <hip/hip_runtime.h>
#include <math.h>

#define Nn 4096
#define Hdim 256
#define Edim 128
#define Cdim 32
#define Vdim 64
#define Kdim 20
#define G4H 1024
#define OUTS 513

#define Rr 32          // rows per tile
#define XP 388         // padded X row stride in floats (384 + 4), 16B-aligned rows
#define WP 36          // padded W tile row stride in floats (32 + 4), 16B-aligned rows

__device__ __forceinline__ float sigmoidf_(float x) { return 1.0f / (1.0f + expf(-x)); }

// ---------------- bucketing ----------------
__global__ void k_zero(int* counts) {
    if (threadIdx.x < 32) counts[threadIdx.x] = 0;
}

__global__ void k_count(const int* __restrict__ cell_id, int* __restrict__ counts) {
    int i = blockIdx.x * blockDim.x + threadIdx.x;
    if (i < Nn) atomicAdd(&counts[cell_id[i]], 1);
}

__global__ void k_scan(const int* __restrict__ counts, int* __restrict__ offs, int* __restrict__ curs) {
    if (threadIdx.x == 0) {
        int acc = 0;
        for (int k = 0; k < Kdim; k++) { offs[k] = acc; curs[k] = acc; acc += counts[k]; }
        offs[Kdim] = acc;
    }
}

__global__ void k_scatter(const int* __restrict__ cell_id, int* __restrict__ curs, int* __restrict__ perm) {
    int i = blockIdx.x * blockDim.x + threadIdx.x;
    if (i < Nn) {
        int p = atomicAdd(&curs[cell_id[i]], 1);
        perm[p] = i;
    }
}

// ---------------- loss kernel: one wave (64 lanes) per row ----------------
__global__ __launch_bounds__(64) void k_loss(
    const float* __restrict__ vec,
    const float* __restrict__ Wlin, const float* __restrict__ blin,
    const float* __restrict__ Wec, const float* __restrict__ bec,
    const float* __restrict__ Wrel, const float* __restrict__ brel,
    const int* __restrict__ category, const int* __restrict__ true_idx,
    const int* __restrict__ ec_idx, const int* __restrict__ rel_idx,
    float* __restrict__ out)
{
    int row = blockIdx.x;
    int lane = threadIdx.x;            // 0..63
    __shared__ float v[Hdim];

    const float* vr = vec + (size_t)row * Hdim;
    ((float4*)v)[lane] = ((const float4*)vr)[lane];   // 64 lanes * 16B = 1KB = 256 floats
    __syncthreads();

    int c = category[row];
    const float* W = Wlin + ((size_t)c * Vdim + lane) * Hdim;
    float acc = 0.0f;
    #pragma unroll 4
    for (int h = 0; h < Hdim; h += 4) {
        float4 w = *(const float4*)(W + h);
        float4 x = *(const float4*)(v + h);
        acc += w.x * x.x + w.y * x.y + w.z * x.z + w.w * x.w;
    }
    float logit = acc + blin[c * Vdim + lane];

    // extra dots: lanes 0..1 -> Wec rows, lanes 2..6 -> Wrel rows
    float extra = 0.0f;
    if (lane < 7) {
        const float* We = (lane < 2) ? (Wec + (size_t)lane * Hdim) : (Wrel + (size_t)(lane - 2) * Hdim);
        float a2 = 0.0f;
        for (int h = 0; h < Hdim; h += 4) {
            float4 w = *(const float4*)(We + h);
            float4 x = *(const float4*)(v + h);
            a2 += w.x * x.x + w.y * x.y + w.z * x.z + w.w * x.w;
        }
        extra = a2;
    }

    // wave softmax-CE over the 64 main logits
    float m = logit;
    for (int s = 32; s >= 1; s >>= 1) m = fmaxf(m, __shfl_xor(m, s));
    float ssum = expf(logit - m);
    for (int s = 32; s >= 1; s >>= 1) ssum += __shfl_xor(ssum, s);
    float lt = __shfl(logit, true_idx[row]);
    float loss = m + logf(ssum) - lt;

    float e0 = __shfl(extra, 0), e1 = __shfl(extra, 1), e2 = __shfl(extra, 2);
    float e3 = __shfl(extra, 3), e4 = __shfl(extra, 4), e5 = __shfl(extra, 5), e6 = __shfl(extra, 6);

    if (lane == 0) {
        // ec CE (2-way)
        float l0 = e0 + bec[0], l1 = e1 + bec[1];
        float me = fmaxf(l0, l1);
        float lse = me + logf(expf(l0 - me) + expf(l1 - me));
        loss += lse - ((ec_idx[row] == 0) ? l0 : l1);
        // rel CE (5-way)
        float r[5] = { e2 + brel[0], e3 + brel[1], e4 + brel[2], e5 + brel[3], e6 + brel[4] };
        float mr = r[0];
        #pragma unroll
        for (int i = 1; i < 5; i++) mr = fmaxf(mr, r[i]);
        float sr = 0.0f;
        #pragma unroll
        for (int i = 0; i < 5; i++) sr += expf(r[i] - mr);
        loss += mr + logf(sr) - r[rel_idx[row]];
        out[(size_t)row * OUTS] = loss;
    }
}

// ---------------- LSTM kernel: 32 bucketed rows x 1024 gates per block ----------------
// grid = (ceil(N/R)=128, K=20); block = 256
// thread t: hh = t&31 (h within 32-tile), rg = t>>5 (row group of 4)
// acc[j][g]: 4 rows x 4 gates at h = hb*32+hh  -> LSTM applied in-register
__global__ __launch_bounds__(256) void k_lstm(
    const float* __restrict__ inp, const float* __restrict__ h_prev, const float* __restrict__ c_prev,
    const float* __restrict__ W_ih, const float* __restrict__ b_ih,
    const float* __restrict__ W_hh, const float* __restrict__ b_hh,
    const int* __restrict__ offs, const int* __restrict__ perm,
    float* __restrict__ out)
{
    __shared__ float Xs[Rr * XP];        // 32 rows x 384 (inp|h_prev), padded
    __shared__ float Wc[128 * WP];       // 128 W-rows x 32 e-chunk, padded
    __shared__ int   rows_s[Rr];

    int k = blockIdx.y;
    int start = offs[k] + blockIdx.x * Rr;
    int end = offs[k + 1];
    if (start >= end) return;
    int rcount = min(Rr, end - start);
    int t = threadIdx.x;
    if (t < Rr) rows_s[t] = perm[start + min(t, rcount - 1)];
    __syncthreads();

    // stage X once: [32][384], e<128 from inp, e>=128 from h_prev
    for (int idx = t; idx < Rr * 96; idx += 256) {
        int r = idx / 96, j = idx % 96;
        int row = rows_s[r];
        float4 val;
        if (j < 32) val = *(const float4*)(inp + (size_t)row * Edim + j * 4);
        else        val = *(const float4*)(h_prev + (size_t)row * Hdim + (j - 32) * 4);
        *(float4*)(&Xs[r * XP + j * 4]) = val;
    }

    const float* Wihk = W_ih + (size_t)k * G4H * Edim;
    const float* Whhk = W_hh + (size_t)k * G4H * Hdim;

    int hh = t & 31;
    int rg = t >> 5;

    for (int hb = 0; hb < 8; hb++) {
        float acc[4][4];
        #pragma unroll
        for (int j = 0; j < 4; j++)
            #pragma unroll
            for (int g = 0; g < 4; g++) acc[j][g] = 0.0f;

        for (int ec = 0; ec < 12; ec++) {
            int eb = ec * 32;
            __syncthreads();   // protect Wc reuse (and X visibility on first iter)
            {
                // stage 128 W-rows x 32 e: thread t loads 16 consecutive floats
                int w_local = t >> 1;
                int q0 = (t & 1) * 16;
                int gate = w_local >> 5;
                int grow = gate * Hdim + hb * 32 + (w_local & 31);
                const float* src;
                int e_in;
                if (eb < Edim) { src = Wihk + (size_t)grow * Edim; e_in = eb; }
                else           { src = Whhk + (size_t)grow * Hdim; e_in = eb - Edim; }
                #pragma unroll
                for (int q = 0; q < 16; q += 4)
                    *(float4*)(&Wc[w_local * WP + q0 + q]) = *(const float4*)(src + e_in + q0 + q);
            }
            __syncthreads();

            #pragma unroll
            for (int e0 = 0; e0 < 32; e0 += 4) {
                float4 xq[4], wq[4];
                #pragma unroll
                for (int j = 0; j < 4; j++) xq[j] = *(const float4*)(&Xs[(rg * 4 + j) * XP + eb + e0]);
                #pragma unroll
                for (int g = 0; g < 4; g++) wq[g] = *(const float4*)(&Wc[(g * 32 + hh) * WP + e0]);
                #pragma unroll
                for (int j = 0; j < 4; j++)
                    #pragma unroll
                    for (int g = 0; g < 4; g++)
                        acc[j][g] += xq[j].x * wq[g].x + xq[j].y * wq[g].y
                                   + xq[j].z * wq[g].z + xq[j].w * wq[g].w;
            }
        }

        int h = hb * 32 + hh;
        float bsum[4];
        #pragma unroll
        for (int g = 0; g < 4; g++)
            bsum[g] = b_ih[(size_t)k * G4H + g * Hdim + h] + b_hh[(size_t)k * G4H + g * Hdim + h];

        #pragma unroll
        for (int j = 0; j < 4; j++) {
            int r = rg * 4 + j;
            if (r < rcount) {
                int row = rows_s[r];
                float iv = acc[j][0] + bsum[0];
                float fv = acc[j][1] + bsum[1];
                float gv = acc[j][2] + bsum[2];
                float ov = acc[j][3] + bsum[3];
                float cp = c_prev[(size_t)row * Hdim + h];
                float cn = sigmoidf_(fv) * cp + sigmoidf_(iv) * tanhf(gv);
                float hn = sigmoidf_(ov) * tanhf(cn);
                out[(size_t)row * OUTS + 1 + h] = hn;
                out[(size_t)row * OUTS + 1 + Hdim + h] = cn;
            }
        }
    }
}

extern "C" void kernel_launch(void* const* d_in, const int* in_sizes, int n_in,
                              void* d_out, int out_size, void* d_ws, size_t ws_size,
                              hipStream_t stream) {
    const float* vec      = (const float*)d_in[0];
    const float* inp      = (const float*)d_in[1];
    const float* h_prev   = (const float*)d_in[2];
    const float* c_prev   = (const float*)d_in[3];
    const float* Wlin     = (const float*)d_in[4];
    const float* blin     = (const float*)d_in[5];
    const float* Wec      = (const float*)d_in[6];
    const float* bec      = (const float*)d_in[7];
    const float* Wrel     = (const float*)d_in[8];
    const float* brel     = (const float*)d_in[9];
    const float* W_ih     = (const float*)d_in[10];
    const float* b_ih     = (const float*)d_in[11];
    const float* W_hh     = (const float*)d_in[12];
    const float* b_hh     = (const float*)d_in[13];
    const int*   category = (const int*)d_in[14];
    const int*   cell_id  = (const int*)d_in[15];
    const int*   true_idx = (const int*)d_in[16];
    const int*   ec_idx   = (const int*)d_in[17];
    const int*   rel_idx  = (const int*)d_in[18];
    float* out = (float*)d_out;

    int* counts = (int*)d_ws;        // 32 ints
    int* offs   = counts + 32;       // K+1 ints
    int* curs   = counts + 64;       // K ints
    int* perm   = counts + 96;       // N ints

    k_zero<<<1, 64, 0, stream>>>(counts);
    k_count<<<Nn / 256, 256, 0, stream>>>(cell_id, counts);
    k_scan<<<1, 64, 0, stream>>>(counts, offs, curs);
    k_scatter<<<Nn / 256, 256, 0, stream>>>(cell_id, curs, perm);

    k_loss<<<Nn, 64, 0, stream>>>(vec, Wlin, blin, Wec, bec, Wrel, brel,
                                  category, true_idx, ec_idx, rel_idx, out);

    dim3 grid(Nn / Rr, Kdim);
    k_lstm<<<grid, 256, 0, stream>>>(inp, h_prev, c_prev, W_ih, b_ih, W_hh, b_hh,
                                     offs, perm, out);
}

// Round 2
// 232.394 us; speedup vs baseline: 3.5308x; 3.5308x over previous
//
#include <hip/hip_runtime.h>
#include <hip/hip_bf16.h>
#include <math.h>

#define Nn 4096
#define Hdim 256
#define Edim 128
#define Cdim 32
#define Vdim 64
#define Kdim 20
#define G4H 1024
#define OUTS 513

#define Rr 32            // rows per GEMM tile
#define MAXTILES 148
#define WSd 72           // LDS row stride in bf16 (36 dwords): balanced banks

typedef short bf16x8 __attribute__((ext_vector_type(8)));
typedef float f32x4 __attribute__((ext_vector_type(4)));

__device__ __forceinline__ float sigmoidf_(float x) { return 1.0f / (1.0f + expf(-x)); }

__device__ __forceinline__ bf16x8 cvt8(float4 f0, float4 f1) {
    bf16x8 r;
    __hip_bfloat16 h;
    h = __float2bfloat16(f0.x); r[0] = *(short*)&h;
    h = __float2bfloat16(f0.y); r[1] = *(short*)&h;
    h = __float2bfloat16(f0.z); r[2] = *(short*)&h;
    h = __float2bfloat16(f0.w); r[3] = *(short*)&h;
    h = __float2bfloat16(f1.x); r[4] = *(short*)&h;
    h = __float2bfloat16(f1.y); r[5] = *(short*)&h;
    h = __float2bfloat16(f1.z); r[6] = *(short*)&h;
    h = __float2bfloat16(f1.w); r[7] = *(short*)&h;
    return r;
}

// ---------------- bucketing ----------------
__global__ void k_zero(int* counts) {
    if (threadIdx.x < 32) counts[threadIdx.x] = 0;
}

__global__ void k_count(const int* __restrict__ cell_id, int* __restrict__ counts) {
    int i = blockIdx.x * blockDim.x + threadIdx.x;
    if (i < Nn) atomicAdd(&counts[cell_id[i]], 1);
}

// builds prefix offsets, scatter cursors, and the exact tile list
// tinfo[0] = tile count; tile i: tinfo[1+2i] = k, tinfo[2+2i] = start | (rcount<<16)
__global__ void k_scan(const int* __restrict__ counts, int* __restrict__ offs,
                       int* __restrict__ curs, int* __restrict__ tinfo) {
    if (threadIdx.x == 0) {
        int acc = 0;
        int nt = 0;
        for (int k = 0; k < Kdim; k++) {
            int c = counts[k];
            offs[k] = acc; curs[k] = acc;
            for (int s = 0; s < c; s += Rr) {
                int rc = (c - s < Rr) ? (c - s) : Rr;
                tinfo[1 + 2 * nt] = k;
                tinfo[2 + 2 * nt] = (acc + s) | (rc << 16);
                nt++;
            }
            acc += c;
        }
        offs[Kdim] = acc;
        tinfo[0] = nt;
    }
}

__global__ void k_scatter(const int* __restrict__ cell_id, int* __restrict__ curs, int* __restrict__ perm) {
    int i = blockIdx.x * blockDim.x + threadIdx.x;
    if (i < Nn) {
        int p = atomicAdd(&curs[cell_id[i]], 1);
        perm[p] = i;
    }
}

// ---------------- loss kernel: one wave (64 lanes) per row ----------------
__global__ __launch_bounds__(64) void k_loss(
    const float* __restrict__ vec,
    const float* __restrict__ Wlin, const float* __restrict__ blin,
    const float* __restrict__ Wec, const float* __restrict__ bec,
    const float* __restrict__ Wrel, const float* __restrict__ brel,
    const int* __restrict__ category, const int* __restrict__ true_idx,
    const int* __restrict__ ec_idx, const int* __restrict__ rel_idx,
    float* __restrict__ out)
{
    int row = blockIdx.x;
    int lane = threadIdx.x;            // 0..63
    __shared__ float v[Hdim];

    const float* vr = vec + (size_t)row * Hdim;
    ((float4*)v)[lane] = ((const float4*)vr)[lane];
    __syncthreads();

    int c = category[row];
    const float* W = Wlin + ((size_t)c * Vdim + lane) * Hdim;
    float acc = 0.0f;
    #pragma unroll 4
    for (int h = 0; h < Hdim; h += 4) {
        float4 w = *(const float4*)(W + h);
        float4 x = *(const float4*)(v + h);
        acc += w.x * x.x + w.y * x.y + w.z * x.z + w.w * x.w;
    }
    float logit = acc + blin[c * Vdim + lane];

    float extra = 0.0f;
    if (lane < 7) {
        const float* We = (lane < 2) ? (Wec + (size_t)lane * Hdim) : (Wrel + (size_t)(lane - 2) * Hdim);
        float a2 = 0.0f;
        for (int h = 0; h < Hdim; h += 4) {
            float4 w = *(const float4*)(We + h);
            float4 x = *(const float4*)(v + h);
            a2 += w.x * x.x + w.y * x.y + w.z * x.z + w.w * x.w;
        }
        extra = a2;
    }

    float m = logit;
    for (int s = 32; s >= 1; s >>= 1) m = fmaxf(m, __shfl_xor(m, s));
    float ssum = expf(logit - m);
    for (int s = 32; s >= 1; s >>= 1) ssum += __shfl_xor(ssum, s);
    float lt = __shfl(logit, true_idx[row]);
    float loss = m + logf(ssum) - lt;

    float e0 = __shfl(extra, 0), e1 = __shfl(extra, 1), e2 = __shfl(extra, 2);
    float e3 = __shfl(extra, 3), e4 = __shfl(extra, 4), e5 = __shfl(extra, 5), e6 = __shfl(extra, 6);

    if (lane == 0) {
        float l0 = e0 + bec[0], l1 = e1 + bec[1];
        float me = fmaxf(l0, l1);
        float lse = me + logf(expf(l0 - me) + expf(l1 - me));
        loss += lse - ((ec_idx[row] == 0) ? l0 : l1);
        float r[5] = { e2 + brel[0], e3 + brel[1], e4 + brel[2], e5 + brel[3], e6 + brel[4] };
        float mr = r[0];
        #pragma unroll
        for (int i = 1; i < 5; i++) mr = fmaxf(mr, r[i]);
        float sr = 0.0f;
        #pragma unroll
        for (int i = 0; i < 5; i++) sr += expf(r[i] - mr);
        loss += mr + logf(sr) - r[rel_idx[row]];
        out[(size_t)row * OUTS] = loss;
    }
}

// ---------------- LSTM via bf16 MFMA ----------------
// grid = (MAXTILES, 4). Block 256 thr = 4 waves.
// Block tile: 32 rows x (64 h x 4 gate types). K = 384 in BK=64 LDS chunks.
// Wave w: 16 h (hb0 + w*16 ..+15), all 4 gates; acc[m(2)][gate(4)] f32x4.
__global__ __launch_bounds__(256) void k_lstm_mfma(
    const float* __restrict__ inp, const float* __restrict__ h_prev, const float* __restrict__ c_prev,
    const float* __restrict__ W_ih, const float* __restrict__ b_ih,
    const float* __restrict__ W_hh, const float* __restrict__ b_hh,
    const int* __restrict__ tinfo, const int* __restrict__ perm,
    float* __restrict__ out)
{
    __shared__ short Ws_[256 * WSd];   // 256 gate-rows x 64 k (bf16, padded)
    __shared__ short Xs_[Rr * WSd];    // 32 rows x 64 k
    __shared__ int rows_s[Rr];

    int tile = blockIdx.x;
    if (tile >= tinfo[0]) return;
    int k = tinfo[1 + 2 * tile];
    int sr = tinfo[2 + 2 * tile];
    int start = sr & 0xFFFF;
    int rcount = sr >> 16;

    int t = threadIdx.x;
    if (t < Rr) rows_s[t] = perm[start + min(t, rcount - 1)];

    int hb0 = blockIdx.y * 64;
    const float* Wih_k = W_ih + (size_t)k * G4H * Edim;
    const float* Whh_k = W_hh + (size_t)k * G4H * Hdim;

    int w = t >> 6;            // wave 0..3
    int l = t & 63;
    int l15 = l & 15, quad = l >> 4;
    int rl_base = t >> 3;      // 0..31
    int kq = t & 7;            // 8 bf16 (16B) per thread per row

    f32x4 acc[2][4];
    #pragma unroll
    for (int m = 0; m < 2; m++)
        #pragma unroll
        for (int g = 0; g < 4; g++)
            acc[m][g] = (f32x4){0.f, 0.f, 0.f, 0.f};

    for (int kb = 0; kb < 6; kb++) {
        int k0 = kb * 64;
        __syncthreads();
        // stage W: 256 rows x 64 k, 8 passes of 32 rows
        #pragma unroll
        for (int p = 0; p < 8; p++) {
            int rl = p * 32 + rl_base;
            int g = rl >> 6, hr = rl & 63;
            int grow = g * Hdim + hb0 + hr;
            const float* src; int ko;
            if (k0 < Edim) { src = Wih_k + (size_t)grow * Edim; ko = k0; }
            else           { src = Whh_k + (size_t)grow * Hdim; ko = k0 - Edim; }
            float4 f0 = *(const float4*)(src + ko + kq * 8);
            float4 f1 = *(const float4*)(src + ko + kq * 8 + 4);
            *(bf16x8*)(&Ws_[rl * WSd + kq * 8]) = cvt8(f0, f1);
        }
        // stage X: 32 rows x 64 k, 1 pass
        {
            int row = rows_s[rl_base];
            const float* src; int ko;
            if (k0 < Edim) { src = inp + (size_t)row * Edim; ko = k0; }
            else           { src = h_prev + (size_t)row * Hdim; ko = k0 - Edim; }
            float4 f0 = *(const float4*)(src + ko + kq * 8);
            float4 f1 = *(const float4*)(src + ko + kq * 8 + 4);
            *(bf16x8*)(&Xs_[rl_base * WSd + kq * 8]) = cvt8(f0, f1);
        }
        __syncthreads();

        #pragma unroll
        for (int ks = 0; ks < 64; ks += 32) {
            bf16x8 af[2], bfr[4];
            #pragma unroll
            for (int m = 0; m < 2; m++)
                af[m] = *(bf16x8*)(&Xs_[(m * 16 + l15) * WSd + ks + quad * 8]);
            #pragma unroll
            for (int g = 0; g < 4; g++)
                bfr[g] = *(bf16x8*)(&Ws_[(g * 64 + w * 16 + l15) * WSd + ks + quad * 8]);
            #pragma unroll
            for (int m = 0; m < 2; m++)
                #pragma unroll
                for (int g = 0; g < 4; g++)
                    acc[m][g] = __builtin_amdgcn_mfma_f32_16x16x32_bf16(af[m], bfr[g], acc[m][g], 0, 0, 0);
        }
    }

    // epilogue: i,f,g,o live in this lane's 4 gate-accumulators at h
    int h = hb0 + w * 16 + l15;
    float bsum[4];
    #pragma unroll
    for (int g = 0; g < 4; g++)
        bsum[g] = b_ih[(size_t)k * G4H + g * Hdim + h] + b_hh[(size_t)k * G4H + g * Hdim + h];

    #pragma unroll
    for (int m = 0; m < 2; m++) {
        #pragma unroll
        for (int reg = 0; reg < 4; reg++) {
            int r = m * 16 + quad * 4 + reg;
            if (r < rcount) {
                int row = rows_s[r];
                float iv = acc[m][0][reg] + bsum[0];
                float fv = acc[m][1][reg] + bsum[1];
                float gv = acc[m][2][reg] + bsum[2];
                float ov = acc[m][3][reg] + bsum[3];
                float cp = c_prev[(size_t)row * Hdim + h];
                float cn = sigmoidf_(fv) * cp + sigmoidf_(iv) * tanhf(gv);
                float hn = sigmoidf_(ov) * tanhf(cn);
                out[(size_t)row * OUTS + 1 + h] = hn;
                out[(size_t)row * OUTS + 1 + Hdim + h] = cn;
            }
        }
    }
}

extern "C" void kernel_launch(void* const* d_in, const int* in_sizes, int n_in,
                              void* d_out, int out_size, void* d_ws, size_t ws_size,
                              hipStream_t stream) {
    const float* vec      = (const float*)d_in[0];
    const float* inp      = (const float*)d_in[1];
    const float* h_prev   = (const float*)d_in[2];
    const float* c_prev   = (const float*)d_in[3];
    const float* Wlin     = (const float*)d_in[4];
    const float* blin     = (const float*)d_in[5];
    const float* Wec      = (const float*)d_in[6];
    const float* bec      = (const float*)d_in[7];
    const float* Wrel     = (const float*)d_in[8];
    const float* brel     = (const float*)d_in[9];
    const float* W_ih     = (const float*)d_in[10];
    const float* b_ih     = (const float*)d_in[11];
    const float* W_hh     = (const float*)d_in[12];
    const float* b_hh     = (const float*)d_in[13];
    const int*   category = (const int*)d_in[14];
    const int*   cell_id  = (const int*)d_in[15];
    const int*   true_idx = (const int*)d_in[16];
    const int*   ec_idx   = (const int*)d_in[17];
    const int*   rel_idx  = (const int*)d_in[18];
    float* out = (float*)d_out;

    int* counts = (int*)d_ws;            // 32
    int* offs   = counts + 32;           // 33 (pad to 40)
    int* curs   = counts + 72;           // 32 (pad to 40)
    int* perm   = counts + 112;          // 4096
    int* tinfo  = perm + Nn;             // 1 + 2*148

    k_zero<<<1, 64, 0, stream>>>(counts);
    k_count<<<Nn / 256, 256, 0, stream>>>(cell_id, counts);
    k_scan<<<1, 64, 0, stream>>>(counts, offs, curs, tinfo);
    k_scatter<<<Nn / 256, 256, 0, stream>>>(cell_id, curs, perm);

    k_loss<<<Nn, 64, 0, stream>>>(vec, Wlin, blin, Wec, bec, Wrel, brel,
                                  category, true_idx, ec_idx, rel_idx, out);

    dim3 grid(MAXTILES, 4);
    k_lstm_mfma<<<grid, 256, 0, stream>>>(inp, h_prev, c_prev, W_ih, b_ih, W_hh, b_hh,
                                          tinfo, perm, out);
}